// Round 2
// baseline (346.233 us; speedup 1.0000x reference)
//
#include <hip/hip_runtime.h>
#include <hip/hip_bf16.h>

// HGRN2: B=4, L=8192, E=1024, H=64, D=2, F=128, BL=32768. fp32 in / fp32 out.
// Pipeline:
//   prep_w : transpose + fp32->bf16 convert weights into ws
//   gemm1  : x@{Wq,Wf,Wi} (bf16 MFMA) + activations -> q,k,v bf16, a fp32, head-major [B*H][L][D]
//   scan   : chunked parallel gated recurrence per (b,h), writes tanh(o) bf16 head-major
//   gemm2  : tanh_o @ Wo -> out fp32 [BL][1024]

typedef __bf16 bf16x8 __attribute__((ext_vector_type(8)));
typedef float f32x4 __attribute__((ext_vector_type(4)));

__device__ __forceinline__ void async16(const void* g, void* l) {
  __builtin_amdgcn_global_load_lds(
      (const __attribute__((address_space(1))) unsigned int*)g,
      (__attribute__((address_space(3))) unsigned int*)l, 16, 0, 0);
}

__device__ __forceinline__ unsigned short f2bf(float f) {
  __hip_bfloat16 h = __float2bfloat16(f);
  return *reinterpret_cast<unsigned short*>(&h);
}
__device__ __forceinline__ float bf2f(unsigned short u) {
  union { unsigned int i; float f; } x; x.i = ((unsigned int)u) << 16; return x.f;
}

// ---------------- weight prep: transpose + cvt ----------------
// Wq/Wf/Wi fp32 [1024][128] -> WT bf16 [3][128][1024];  Wo fp32 [128][1024] -> WoT bf16 [1024][128]
__global__ __launch_bounds__(256) void prep_w(
    const float* __restrict__ Wq, const float* __restrict__ Wf,
    const float* __restrict__ Wi, const float* __restrict__ Wo,
    unsigned short* __restrict__ WT, unsigned short* __restrict__ WoT) {
  int idx = blockIdx.x * 256 + threadIdx.x;
  if (idx < 393216) {
    int which = idx >> 17;
    int r = idx & 131071;
    int k = r >> 7, n = r & 127;
    const float* W = (which == 0) ? Wq : ((which == 1) ? Wf : Wi);
    WT[which * 131072 + n * 1024 + k] = f2bf(W[r]);
  } else {
    int r = idx - 393216;
    int k = r >> 10, n = r & 1023;
    WoT[n * 128 + k] = f2bf(Wo[r]);
  }
}

// ---------------- GEMM1 + activations ----------------
// grid (3, 256): x = sel(0=q,1=f,2=i), y = row-block (128 rows of BL).
__global__ __launch_bounds__(256) void gemm1_kernel(
    const float* __restrict__ X, const unsigned short* __restrict__ WTall,
    unsigned short* __restrict__ qb, unsigned short* __restrict__ kb,
    unsigned short* __restrict__ vb, float* __restrict__ af) {
  __shared__ __align__(128) char smem[32768];  // A:16KB (bf16 128x64), B:16KB
  const int t = threadIdx.x;
  const int lane = t & 63, w = t >> 6;
  const int quad = lane >> 4, c15 = lane & 15;
  const int wm = w >> 1, wn = w & 1;
  const int sel = blockIdx.x;
  const int row0 = blockIdx.y * 128;
  const unsigned short* Wt = WTall + (size_t)sel * 131072;

  // B staging (async16): per-lane row/chunk
  const int lrow = t >> 3;              // 0..31
  const int ch = (t & 7) ^ (lrow & 7);  // xor-swizzled k-chunk fetched
  // A staging (regs->LDS): 16 threads per 16-row group cover 64 floats
  const int ar = t >> 4;          // 0..15 row sub
  const int ac = (t & 15) >> 1;   // k-chunk 0..7
  const int ah = t & 1;           // half of 16B slot
  const int ak = (t & 15) * 4;    // k float offset 0..60

  f32x4 acc[4][4];
#pragma unroll
  for (int i = 0; i < 4; i++)
#pragma unroll
    for (int j = 0; j < 4; j++) acc[i][j] = (f32x4){0.f, 0.f, 0.f, 0.f};

  for (int kt = 0; kt < 16; ++kt) {
    float4 av[8];
#pragma unroll
    for (int i = 0; i < 8; ++i)
      av[i] = *(const float4*)(X + (size_t)(row0 + i * 16 + ar) * 1024 + kt * 64 + ak);
    __syncthreads();  // previous iteration's MFMA reads complete
#pragma unroll
    for (int c = 0; c < 4; ++c)
      async16(Wt + (size_t)(c * 32 + lrow) * 1024 + kt * 64 + ch * 8,
              smem + 16384 + c * 4096 + w * 1024);
#pragma unroll
    for (int i = 0; i < 8; ++i) {
      const int r = i * 16 + ar;
      short4 s4;
      s4.x = (short)f2bf(av[i].x); s4.y = (short)f2bf(av[i].y);
      s4.z = (short)f2bf(av[i].z); s4.w = (short)f2bf(av[i].w);
      *(short4*)(smem + r * 128 + ((ac ^ (r & 7)) << 4) + ah * 8) = s4;
    }
    __syncthreads();  // drains ds_write + async16 (vmcnt) before reads
#pragma unroll
    for (int ks = 0; ks < 2; ++ks) {
      bf16x8 afr[4], bfr[4];
      const int ck = ks * 4 + quad;
#pragma unroll
      for (int mi = 0; mi < 4; ++mi) {
        const int m = wm * 64 + mi * 16 + c15;
        afr[mi] = *(const bf16x8*)(smem + m * 128 + ((ck ^ (m & 7)) << 4));
      }
#pragma unroll
      for (int ni = 0; ni < 4; ++ni) {
        const int n = wn * 64 + ni * 16 + c15;
        bfr[ni] = *(const bf16x8*)(smem + 16384 + n * 128 + ((ck ^ (n & 7)) << 4));
      }
#pragma unroll
      for (int mi = 0; mi < 4; ++mi)
#pragma unroll
        for (int ni = 0; ni < 4; ++ni)
          acc[mi][ni] = __builtin_amdgcn_mfma_f32_16x16x32_bf16(afr[mi], bfr[ni], acc[mi][ni], 0, 0, 0);
    }
  }
  // epilogue: activation + scatter to head-major [B*H][L][D]
#pragma unroll
  for (int mi = 0; mi < 4; ++mi) {
#pragma unroll
    for (int ni = 0; ni < 4; ++ni) {
#pragma unroll
      for (int r2 = 0; r2 < 4; ++r2) {
        float val = acc[mi][ni][r2];
        const int m = wm * 64 + mi * 16 + quad * 4 + r2;
        const int n = wn * 64 + ni * 16 + c15;
        const int grow = row0 + m;
        const int bb = grow >> 13, l = grow & 8191;
        const int h = n >> 1, d = n & 1;
        const size_t idx = (size_t)(bb * 64 + h) * 16384 + l * 2 + d;
        if (sel == 0) {
          qb[idx] = f2bf(0.5f * val * (1.f + erff(val * 0.70710678118654752f)));
        } else if (sel == 1) {
          float s  = 1.f / (1.f + expf(-val));  // sigmoid(f), inf-safe
          float ks = 1.f / (1.f + expf(val));   // 1 - sigmoid(f), inf-safe
          kb[idx] = f2bf(ks);
          af[idx] = s + 1e-6f;                  // exp(log(sig+1e-6)) == sig+1e-6
        } else {
          vb[idx] = f2bf(val);
        }
      }
    }
  }
}

// ---------------- scan ----------------
struct C6 { float A0, A1, B00, B01, B10, B11; };
__device__ __forceinline__ C6 comb(const C6& p, const C6& c) {
  C6 r;
  r.A0 = p.A0 * c.A0; r.A1 = p.A1 * c.A1;
  r.B00 = c.A0 * p.B00 + c.B00; r.B01 = c.A0 * p.B01 + c.B01;
  r.B10 = c.A1 * p.B10 + c.B10; r.B11 = c.A1 * p.B11 + c.B11;
  return r;
}
__device__ __forceinline__ C6 shflup(const C6& c, unsigned d) {
  C6 r;
  r.A0 = __shfl_up(c.A0, d); r.A1 = __shfl_up(c.A1, d);
  r.B00 = __shfl_up(c.B00, d); r.B01 = __shfl_up(c.B01, d);
  r.B10 = __shfl_up(c.B10, d); r.B11 = __shfl_up(c.B11, d);
  return r;
}
__device__ __forceinline__ void ld8bf(const unsigned short* p, float* dst) {
  union { int4 v; unsigned short u[8]; } x;
  x.v = *(const int4*)p;
#pragma unroll
  for (int j = 0; j < 8; ++j) dst[j] = bf2f(x.u[j]);
}

__global__ __launch_bounds__(256) void scan_kernel(
    const unsigned short* __restrict__ qb, const unsigned short* __restrict__ kb,
    const unsigned short* __restrict__ vb, const float* __restrict__ af,
    unsigned short* __restrict__ ob) {
  const int t = threadIdx.x, lane = t & 63, w = t >> 6;
  __shared__ C6 cw[2][4];
  const size_t base = (size_t)blockIdx.x * 16384;
  float P00 = 0.f, P01 = 0.f, P10 = 0.f, P11 = 0.f;

  for (int i = 0; i < 4; ++i) {
    const int e0 = i * 4096 + t * 16;  // element offset (16 = 8 steps * D)
    float q[16], k[16], v[16], a[16];
    ld8bf(qb + base + e0, q); ld8bf(qb + base + e0 + 8, q + 8);
    ld8bf(kb + base + e0, k); ld8bf(kb + base + e0 + 8, k + 8);
    ld8bf(vb + base + e0, v); ld8bf(vb + base + e0 + 8, v + 8);
#pragma unroll
    for (int j = 0; j < 4; j++) ((float4*)a)[j] = ((const float4*)(af + base + e0))[j];

    // phase 1: local transform over 8 steps
    C6 c = {1.f, 1.f, 0.f, 0.f, 0.f, 0.f};
#pragma unroll
    for (int j = 0; j < 8; j++) {
      float a0 = a[2 * j], a1 = a[2 * j + 1], k0 = k[2 * j], k1 = k[2 * j + 1];
      float v0 = v[2 * j], v1 = v[2 * j + 1];
      c.A0 *= a0; c.A1 *= a1;
      c.B00 = a0 * c.B00 + k0 * v0; c.B01 = a0 * c.B01 + k0 * v1;
      c.B10 = a1 * c.B10 + k1 * v0; c.B11 = a1 * c.B11 + k1 * v1;
    }
    // wave inclusive scan
    C6 inc = c;
#pragma unroll
    for (int d = 1; d < 64; d <<= 1) {
      C6 u = shflup(inc, d);
      if (lane >= d) inc = comb(u, inc);
    }
    if (lane == 63) cw[i & 1][w] = inc;
    __syncthreads();
    C6 wp = {1.f, 1.f, 0.f, 0.f, 0.f, 0.f};
    for (int ww = 0; ww < w; ++ww) wp = comb(wp, cw[i & 1][ww]);
    C6 tot = cw[i & 1][0];
    for (int ww = 1; ww < 4; ++ww) tot = comb(tot, cw[i & 1][ww]);
    C6 ex = shflup(inc, 1);
    if (lane == 0) ex = (C6){1.f, 1.f, 0.f, 0.f, 0.f, 0.f};
    C6 te = comb(wp, ex);
    float S00 = te.A0 * P00 + te.B00, S01 = te.A0 * P01 + te.B01;
    float S10 = te.A1 * P10 + te.B10, S11 = te.A1 * P11 + te.B11;
    // phase 2: replay + output
    union { int4 v[2]; unsigned short u[16]; } ou;
#pragma unroll
    for (int j = 0; j < 8; j++) {
      float a0 = a[2 * j], a1 = a[2 * j + 1], k0 = k[2 * j], k1 = k[2 * j + 1];
      float v0 = v[2 * j], v1 = v[2 * j + 1];
      S00 = a0 * S00 + k0 * v0; S01 = a0 * S01 + k0 * v1;
      S10 = a1 * S10 + k1 * v0; S11 = a1 * S11 + k1 * v1;
      float o0 = 0.70710678118654752f * (q[2 * j] * S00 + q[2 * j + 1] * S10);
      float o1 = 0.70710678118654752f * (q[2 * j] * S01 + q[2 * j + 1] * S11);
      ou.u[2 * j] = f2bf(tanhf(o0));
      ou.u[2 * j + 1] = f2bf(tanhf(o1));
    }
    *(int4*)(ob + base + e0) = ou.v[0];
    *(int4*)(ob + base + e0 + 8) = ou.v[1];
    // carry across tiles
    float nP00 = tot.A0 * P00 + tot.B00, nP01 = tot.A0 * P01 + tot.B01;
    float nP10 = tot.A1 * P10 + tot.B10, nP11 = tot.A1 * P11 + tot.B11;
    P00 = nP00; P01 = nP01; P10 = nP10; P11 = nP11;
  }
}

// ---------------- GEMM2 ----------------
// grid (8, 512): x = n-block (128 cols of E), y = row-block (64 rows of BL).
__global__ __launch_bounds__(256) void gemm2_kernel(
    const unsigned short* __restrict__ ob, const unsigned short* __restrict__ WoT,
    float* __restrict__ out) {
  __shared__ __align__(128) char smem[49152];  // A:16KB (64x128 bf16, xor-swizzled), B:32KB
  const int t = threadIdx.x, lane = t & 63, w = t >> 6;
  const int quad = lane >> 4, c15 = lane & 15;
  const int n0 = blockIdx.x * 128;
  const int row0 = blockIdx.y * 64;
  const int bb = row0 >> 13;
  const int l0 = row0 & 8191;
  // stage A: tanh_o head-major -> LDS [l][f] with 16B xor swizzle
  {
    const int h = t & 63, q2 = t >> 6;
    const unsigned short* g = ob + (size_t)(bb * 64 + h) * 16384 + (size_t)(l0 + q2 * 16) * 2;
    const int cbase = h >> 2;
    const int ioff = (h & 3) * 4;
#pragma unroll
    for (int i = 0; i < 4; i++) {
      union { int4 v; unsigned int u[4]; } d4;
      d4.v = *(const int4*)(g + i * 8);
#pragma unroll
      for (int jj = 0; jj < 4; jj++) {
        const int lrr = q2 * 16 + i * 4 + jj;
        *(unsigned int*)(smem + lrr * 256 + ((cbase ^ (lrr & 15)) << 4) + ioff) = d4.u[jj];
      }
    }
  }
  // stage B: WoT rows n0..n0+127 (256B each) via global_load_lds
  {
    const int rr = t >> 4;
    const int ch = (t & 15) ^ rr;
#pragma unroll
    for (int c = 0; c < 8; c++) {
      async16(WoT + (size_t)(n0 + c * 16 + rr) * 128 + ch * 8,
              smem + 16384 + c * 4096 + w * 1024);
    }
  }
  __syncthreads();
  f32x4 acc[4][2];
#pragma unroll
  for (int i = 0; i < 4; i++) { acc[i][0] = (f32x4){0.f,0.f,0.f,0.f}; acc[i][1] = (f32x4){0.f,0.f,0.f,0.f}; }
#pragma unroll
  for (int ks = 0; ks < 4; ++ks) {
    bf16x8 afr[4], bfr[2];
    const int ck = ks * 4 + quad;
#pragma unroll
    for (int mi = 0; mi < 4; ++mi) {
      const int m = mi * 16 + c15;
      afr[mi] = *(const bf16x8*)(smem + m * 256 + ((ck ^ (m & 15)) << 4));
    }
#pragma unroll
    for (int ni = 0; ni < 2; ++ni) {
      const int n = w * 32 + ni * 16 + c15;
      bfr[ni] = *(const bf16x8*)(smem + 16384 + n * 256 + ((ck ^ (n & 15)) << 4));
    }
#pragma unroll
    for (int mi = 0; mi < 4; ++mi)
#pragma unroll
      for (int ni = 0; ni < 2; ++ni)
        acc[mi][ni] = __builtin_amdgcn_mfma_f32_16x16x32_bf16(afr[mi], bfr[ni], acc[mi][ni], 0, 0, 0);
  }
#pragma unroll
  for (int mi = 0; mi < 4; ++mi)
#pragma unroll
    for (int ni = 0; ni < 2; ++ni)
#pragma unroll
      for (int r2 = 0; r2 < 4; ++r2) {
        const int m = mi * 16 + quad * 4 + r2;
        const int n = n0 + w * 32 + ni * 16 + c15;
        out[(size_t)(row0 + m) * 1024 + n] = acc[mi][ni][r2];
      }
}

// ---------------- launch ----------------
extern "C" void kernel_launch(void* const* d_in, const int* in_sizes, int n_in,
                              void* d_out, int out_size, void* d_ws, size_t ws_size,
                              hipStream_t stream) {
  const float* x  = (const float*)d_in[0];
  const float* Wq = (const float*)d_in[1];
  const float* Wf = (const float*)d_in[2];
  const float* Wi = (const float*)d_in[3];
  const float* Wo = (const float*)d_in[4];
  float* out = (float*)d_out;
  char* ws = (char*)d_ws;

  unsigned short* WT  = (unsigned short*)(ws);                       // 3 x [128][1024] bf16
  unsigned short* WoT = (unsigned short*)(ws + 786432);              // [1024][128] bf16
  unsigned short* qb  = (unsigned short*)(ws + 1048576);             // [B*H][L][D] bf16
  unsigned short* kb  = (unsigned short*)(ws + 1048576 + 8388608);
  unsigned short* vb  = (unsigned short*)(ws + 1048576 + 16777216);
  float*          af  = (float*)(ws + 1048576 + 25165824);           // fp32 decay
  unsigned short* ob  = (unsigned short*)(ws + 1048576 + 41943040);  // tanh(o) bf16

  prep_w<<<2048, 256, 0, stream>>>(Wq, Wf, Wi, Wo, WT, WoT);
  gemm1_kernel<<<dim3(3, 256), 256, 0, stream>>>(x, WT, qb, kb, vb, af);
  scan_kernel<<<256, 256, 0, stream>>>(qb, kb, vb, af, ob);
  gemm2_kernel<<<dim3(8, 512), 256, 0, stream>>>(ob, WoT, out);
}

// Round 3
// 314.454 us; speedup vs baseline: 1.1011x; 1.1011x over previous
//
#include <hip/hip_runtime.h>
#include <hip/hip_bf16.h>

// HGRN2: B=4, L=8192, E=1024, H=64, D=2, F=128, BL=32768. fp32 in / fp32 out.
// Pipeline:
//   prep_w : transpose + fp32->bf16 convert weights into ws
//   gemm1  : x@{Wq,Wf,Wi} FUSED (reads x once) + activations -> q,k,v bf16, a fp32, head-major
//   scan   : chunked parallel gated recurrence per (b,h), writes tanh(o) bf16 head-major
//   gemm2  : tanh_o @ Wo -> out fp32 [BL][1024]

typedef __bf16 bf16x8 __attribute__((ext_vector_type(8)));
typedef float f32x4 __attribute__((ext_vector_type(4)));

__device__ __forceinline__ void async16(const void* g, void* l) {
  __builtin_amdgcn_global_load_lds(
      (const __attribute__((address_space(1))) unsigned int*)g,
      (__attribute__((address_space(3))) unsigned int*)l, 16, 0, 0);
}

__device__ __forceinline__ unsigned short f2bf(float f) {
  __hip_bfloat16 h = __float2bfloat16(f);
  return *reinterpret_cast<unsigned short*>(&h);
}
__device__ __forceinline__ float bf2f(unsigned short u) {
  union { unsigned int i; float f; } x; x.i = ((unsigned int)u) << 16; return x.f;
}

// ---------------- weight prep: transpose + cvt ----------------
// Wq/Wf/Wi fp32 [1024][128] -> WT bf16 [3][128][1024];  Wo fp32 [128][1024] -> WoT bf16 [1024][128]
__global__ __launch_bounds__(256) void prep_w(
    const float* __restrict__ Wq, const float* __restrict__ Wf,
    const float* __restrict__ Wi, const float* __restrict__ Wo,
    unsigned short* __restrict__ WT, unsigned short* __restrict__ WoT) {
  int idx = blockIdx.x * 256 + threadIdx.x;
  if (idx < 393216) {
    int which = idx >> 17;
    int r = idx & 131071;
    int k = r >> 7, n = r & 127;
    const float* W = (which == 0) ? Wq : ((which == 1) ? Wf : Wi);
    WT[which * 131072 + n * 1024 + k] = f2bf(W[r]);
  } else {
    int r = idx - 393216;
    int k = r >> 10, n = r & 1023;
    WoT[n * 128 + k] = f2bf(Wo[r]);
  }
}

// ---------------- GEMM1 fused (q,f,i) + activations ----------------
// grid 512: block owns 64 rows of BL, computes all 3x128 output cols.
// LDS: A 64x64 bf16 (8KB, xor-swizzled 16B chunks), B 3 x 128x64 bf16 (48KB).
__global__ __launch_bounds__(256, 2) void gemm1_kernel(
    const float* __restrict__ X, const unsigned short* __restrict__ WTall,
    unsigned short* __restrict__ qb, unsigned short* __restrict__ kb,
    unsigned short* __restrict__ vb, float* __restrict__ af) {
  __shared__ __align__(128) char smem[57344];
  const int t = threadIdx.x;
  const int lane = t & 63, w = t >> 6;
  const int quad = lane >> 4, c15 = lane & 15;
  const int wm = w >> 1, wn = w & 1;
  const int row0 = blockIdx.x * 64;

  // B staging (async16): per-call row r = c*32 + (t>>3), fetched chunk xor-swizzled
  const int br = t >> 3;                 // 0..31
  const int bch = (t & 7) ^ (br & 7);
  // A staging: thread covers 16 consecutive floats of row ar (coalesced 64B)
  const int ar = t >> 2;                 // 0..63
  const int akf = (t & 3) * 16;          // k float offset
  const int ac0 = (t & 3) * 2;           // first bf16 8-elem chunk

  f32x4 acc[3][2][4];
#pragma unroll
  for (int s = 0; s < 3; ++s)
#pragma unroll
    for (int i = 0; i < 2; ++i)
#pragma unroll
      for (int j = 0; j < 4; ++j) acc[s][i][j] = (f32x4){0.f, 0.f, 0.f, 0.f};

  for (int kt = 0; kt < 16; ++kt) {
    float4 av[4];
    const float* xp = X + (size_t)(row0 + ar) * 1024 + kt * 64 + akf;
#pragma unroll
    for (int i = 0; i < 4; ++i) av[i] = *(const float4*)(xp + i * 4);
    __syncthreads();  // previous iteration's LDS reads complete
#pragma unroll
    for (int s = 0; s < 3; ++s)
#pragma unroll
      for (int c = 0; c < 4; ++c)
        async16(WTall + (size_t)s * 131072 + (size_t)(c * 32 + br) * 1024 + kt * 64 + bch * 8,
                smem + 8192 + s * 16384 + c * 4096 + w * 1024);
    {
      union { unsigned short u[16]; int4 v[2]; } p;
#pragma unroll
      for (int i = 0; i < 4; ++i) {
        p.u[4 * i + 0] = f2bf(av[i].x); p.u[4 * i + 1] = f2bf(av[i].y);
        p.u[4 * i + 2] = f2bf(av[i].z); p.u[4 * i + 3] = f2bf(av[i].w);
      }
      *(int4*)(smem + ar * 128 + (((ac0 + 0) ^ (ar & 7)) << 4)) = p.v[0];
      *(int4*)(smem + ar * 128 + (((ac0 + 1) ^ (ar & 7)) << 4)) = p.v[1];
    }
    __syncthreads();  // drains ds_write + async16 before fragment reads
#pragma unroll
    for (int ks = 0; ks < 2; ++ks) {
      const int ck = ks * 4 + quad;
      bf16x8 afr[2], bfr[3][4];
#pragma unroll
      for (int mi = 0; mi < 2; ++mi) {
        const int m = wm * 32 + mi * 16 + c15;
        afr[mi] = *(const bf16x8*)(smem + m * 128 + ((ck ^ (m & 7)) << 4));
      }
#pragma unroll
      for (int s = 0; s < 3; ++s)
#pragma unroll
        for (int ni = 0; ni < 4; ++ni) {
          const int n = wn * 64 + ni * 16 + c15;
          bfr[s][ni] = *(const bf16x8*)(smem + 8192 + s * 16384 + n * 128 + ((ck ^ (n & 7)) << 4));
        }
#pragma unroll
      for (int s = 0; s < 3; ++s)
#pragma unroll
        for (int mi = 0; mi < 2; ++mi)
#pragma unroll
          for (int ni = 0; ni < 4; ++ni)
            acc[s][mi][ni] = __builtin_amdgcn_mfma_f32_16x16x32_bf16(afr[mi], bfr[s][ni], acc[s][mi][ni], 0, 0, 0);
    }
  }
  // epilogue: activation + scatter to head-major [B*H][L][D]
#pragma unroll
  for (int s = 0; s < 3; ++s) {
#pragma unroll
    for (int mi = 0; mi < 2; ++mi) {
#pragma unroll
      for (int ni = 0; ni < 4; ++ni) {
#pragma unroll
        for (int r2 = 0; r2 < 4; ++r2) {
          float val = acc[s][mi][ni][r2];
          const int m = wm * 32 + mi * 16 + quad * 4 + r2;
          const int n = wn * 64 + ni * 16 + c15;
          const int grow = row0 + m;
          const int bb = grow >> 13, l = grow & 8191;
          const int h = n >> 1, d = n & 1;
          const size_t idx = (size_t)(bb * 64 + h) * 16384 + l * 2 + d;
          if (s == 0) {
            qb[idx] = f2bf(0.5f * val * (1.f + erff(val * 0.70710678118654752f)));
          } else if (s == 1) {
            float sg = 1.f / (1.f + expf(-val));  // sigmoid(f), inf-safe
            float ks = 1.f / (1.f + expf(val));   // 1 - sigmoid(f), inf-safe
            kb[idx] = f2bf(ks);
            af[idx] = sg + 1e-6f;                 // exp(log(sig+1e-6)) == sig+1e-6
          } else {
            vb[idx] = f2bf(val);
          }
        }
      }
    }
  }
}

// ---------------- scan ----------------
struct C6 { float A0, A1, B00, B01, B10, B11; };
__device__ __forceinline__ C6 comb(const C6& p, const C6& c) {
  C6 r;
  r.A0 = p.A0 * c.A0; r.A1 = p.A1 * c.A1;
  r.B00 = c.A0 * p.B00 + c.B00; r.B01 = c.A0 * p.B01 + c.B01;
  r.B10 = c.A1 * p.B10 + c.B10; r.B11 = c.A1 * p.B11 + c.B11;
  return r;
}
__device__ __forceinline__ C6 shflup(const C6& c, unsigned d) {
  C6 r;
  r.A0 = __shfl_up(c.A0, d); r.A1 = __shfl_up(c.A1, d);
  r.B00 = __shfl_up(c.B00, d); r.B01 = __shfl_up(c.B01, d);
  r.B10 = __shfl_up(c.B10, d); r.B11 = __shfl_up(c.B11, d);
  return r;
}
__device__ __forceinline__ void ld8bf(const unsigned short* p, float* dst) {
  union { int4 v; unsigned short u[8]; } x;
  x.v = *(const int4*)p;
#pragma unroll
  for (int j = 0; j < 8; ++j) dst[j] = bf2f(x.u[j]);
}

__global__ __launch_bounds__(256) void scan_kernel(
    const unsigned short* __restrict__ qb, const unsigned short* __restrict__ kb,
    const unsigned short* __restrict__ vb, const float* __restrict__ af,
    unsigned short* __restrict__ ob) {
  const int t = threadIdx.x, lane = t & 63, w = t >> 6;
  __shared__ C6 cw[2][4];
  const size_t base = (size_t)blockIdx.x * 16384;
  float P00 = 0.f, P01 = 0.f, P10 = 0.f, P11 = 0.f;

  for (int i = 0; i < 4; ++i) {
    const int e0 = i * 4096 + t * 16;  // element offset (16 = 8 steps * D)
    float q[16], k[16], v[16], a[16];
    ld8bf(qb + base + e0, q); ld8bf(qb + base + e0 + 8, q + 8);
    ld8bf(kb + base + e0, k); ld8bf(kb + base + e0 + 8, k + 8);
    ld8bf(vb + base + e0, v); ld8bf(vb + base + e0 + 8, v + 8);
#pragma unroll
    for (int j = 0; j < 4; j++) ((float4*)a)[j] = ((const float4*)(af + base + e0))[j];

    // phase 1: local transform over 8 steps
    C6 c = {1.f, 1.f, 0.f, 0.f, 0.f, 0.f};
#pragma unroll
    for (int j = 0; j < 8; j++) {
      float a0 = a[2 * j], a1 = a[2 * j + 1], k0 = k[2 * j], k1 = k[2 * j + 1];
      float v0 = v[2 * j], v1 = v[2 * j + 1];
      c.A0 *= a0; c.A1 *= a1;
      c.B00 = a0 * c.B00 + k0 * v0; c.B01 = a0 * c.B01 + k0 * v1;
      c.B10 = a1 * c.B10 + k1 * v0; c.B11 = a1 * c.B11 + k1 * v1;
    }
    // wave inclusive scan
    C6 inc = c;
#pragma unroll
    for (int d = 1; d < 64; d <<= 1) {
      C6 u = shflup(inc, d);
      if (lane >= d) inc = comb(u, inc);
    }
    if (lane == 63) cw[i & 1][w] = inc;
    __syncthreads();
    C6 wp = {1.f, 1.f, 0.f, 0.f, 0.f, 0.f};
    for (int ww = 0; ww < w; ++ww) wp = comb(wp, cw[i & 1][ww]);
    C6 tot = cw[i & 1][0];
    for (int ww = 1; ww < 4; ++ww) tot = comb(tot, cw[i & 1][ww]);
    C6 ex = shflup(inc, 1);
    if (lane == 0) ex = (C6){1.f, 1.f, 0.f, 0.f, 0.f, 0.f};
    C6 te = comb(wp, ex);
    float S00 = te.A0 * P00 + te.B00, S01 = te.A0 * P01 + te.B01;
    float S10 = te.A1 * P10 + te.B10, S11 = te.A1 * P11 + te.B11;
    // phase 2: replay + output
    union { int4 v[2]; unsigned short u[16]; } ou;
#pragma unroll
    for (int j = 0; j < 8; j++) {
      float a0 = a[2 * j], a1 = a[2 * j + 1], k0 = k[2 * j], k1 = k[2 * j + 1];
      float v0 = v[2 * j], v1 = v[2 * j + 1];
      S00 = a0 * S00 + k0 * v0; S01 = a0 * S01 + k0 * v1;
      S10 = a1 * S10 + k1 * v0; S11 = a1 * S11 + k1 * v1;
      float o0 = 0.70710678118654752f * (q[2 * j] * S00 + q[2 * j + 1] * S10);
      float o1 = 0.70710678118654752f * (q[2 * j] * S01 + q[2 * j + 1] * S11);
      ou.u[2 * j] = f2bf(tanhf(o0));
      ou.u[2 * j + 1] = f2bf(tanhf(o1));
    }
    *(int4*)(ob + base + e0) = ou.v[0];
    *(int4*)(ob + base + e0 + 8) = ou.v[1];
    // carry across tiles
    float nP00 = tot.A0 * P00 + tot.B00, nP01 = tot.A0 * P01 + tot.B01;
    float nP10 = tot.A1 * P10 + tot.B10, nP11 = tot.A1 * P11 + tot.B11;
    P00 = nP00; P01 = nP01; P10 = nP10; P11 = nP11;
  }
}

// ---------------- GEMM2 ----------------
// grid (8, 512): x = n-block (128 cols of E), y = row-block (64 rows of BL).
__global__ __launch_bounds__(256) void gemm2_kernel(
    const unsigned short* __restrict__ ob, const unsigned short* __restrict__ WoT,
    float* __restrict__ out) {
  __shared__ __align__(128) char smem[49152];  // A:16KB (64x128 bf16, xor-swizzled), B:32KB
  const int t = threadIdx.x, lane = t & 63, w = t >> 6;
  const int quad = lane >> 4, c15 = lane & 15;
  const int n0 = blockIdx.x * 128;
  const int row0 = blockIdx.y * 64;
  const int bb = row0 >> 13;
  const int l0 = row0 & 8191;
  // stage A: tanh_o head-major -> LDS [l][f] with 16B xor swizzle
  {
    const int h = t & 63, q2 = t >> 6;
    const unsigned short* g = ob + (size_t)(bb * 64 + h) * 16384 + (size_t)(l0 + q2 * 16) * 2;
    const int cbase = h >> 2;
    const int ioff = (h & 3) * 4;
#pragma unroll
    for (int i = 0; i < 4; i++) {
      union { int4 v; unsigned int u[4]; } d4;
      d4.v = *(const int4*)(g + i * 8);
#pragma unroll
      for (int jj = 0; jj < 4; jj++) {
        const int lrr = q2 * 16 + i * 4 + jj;
        *(unsigned int*)(smem + lrr * 256 + ((cbase ^ (lrr & 15)) << 4) + ioff) = d4.u[jj];
      }
    }
  }
  // stage B: WoT rows n0..n0+127 (256B each) via global_load_lds
  {
    const int rr = t >> 4;
    const int ch = (t & 15) ^ rr;
#pragma unroll
    for (int c = 0; c < 8; c++) {
      async16(WoT + (size_t)(n0 + c * 16 + rr) * 128 + ch * 8,
              smem + 16384 + c * 4096 + w * 1024);
    }
  }
  __syncthreads();
  f32x4 acc[4][2];
#pragma unroll
  for (int i = 0; i < 4; i++) { acc[i][0] = (f32x4){0.f,0.f,0.f,0.f}; acc[i][1] = (f32x4){0.f,0.f,0.f,0.f}; }
#pragma unroll
  for (int ks = 0; ks < 4; ++ks) {
    bf16x8 afr[4], bfr[2];
    const int ck = ks * 4 + quad;
#pragma unroll
    for (int mi = 0; mi < 4; ++mi) {
      const int m = mi * 16 + c15;
      afr[mi] = *(const bf16x8*)(smem + m * 256 + ((ck ^ (m & 15)) << 4));
    }
#pragma unroll
    for (int ni = 0; ni < 2; ++ni) {
      const int n = w * 32 + ni * 16 + c15;
      bfr[ni] = *(const bf16x8*)(smem + 16384 + n * 256 + ((ck ^ (n & 15)) << 4));
    }
#pragma unroll
    for (int mi = 0; mi < 4; ++mi)
#pragma unroll
      for (int ni = 0; ni < 2; ++ni)
        acc[mi][ni] = __builtin_amdgcn_mfma_f32_16x16x32_bf16(afr[mi], bfr[ni], acc[mi][ni], 0, 0, 0);
  }
#pragma unroll
  for (int mi = 0; mi < 4; ++mi)
#pragma unroll
    for (int ni = 0; ni < 2; ++ni)
#pragma unroll
      for (int r2 = 0; r2 < 4; ++r2) {
        const int m = mi * 16 + quad * 4 + r2;
        const int n = n0 + w * 32 + ni * 16 + c15;
        out[(size_t)(row0 + m) * 1024 + n] = acc[mi][ni][r2];
      }
}

// ---------------- launch ----------------
extern "C" void kernel_launch(void* const* d_in, const int* in_sizes, int n_in,
                              void* d_out, int out_size, void* d_ws, size_t ws_size,
                              hipStream_t stream) {
  const float* x  = (const float*)d_in[0];
  const float* Wq = (const float*)d_in[1];
  const float* Wf = (const float*)d_in[2];
  const float* Wi = (const float*)d_in[3];
  const float* Wo = (const float*)d_in[4];
  float* out = (float*)d_out;
  char* ws = (char*)d_ws;

  unsigned short* WT  = (unsigned short*)(ws);                       // 3 x [128][1024] bf16
  unsigned short* WoT = (unsigned short*)(ws + 786432);              // [1024][128] bf16
  unsigned short* qb  = (unsigned short*)(ws + 1048576);             // [B*H][L][D] bf16
  unsigned short* kb  = (unsigned short*)(ws + 1048576 + 8388608);
  unsigned short* vb  = (unsigned short*)(ws + 1048576 + 16777216);
  float*          af  = (float*)(ws + 1048576 + 25165824);           // fp32 decay
  unsigned short* ob  = (unsigned short*)(ws + 1048576 + 41943040);  // tanh(o) bf16

  prep_w<<<2048, 256, 0, stream>>>(Wq, Wf, Wi, Wo, WT, WoT);
  gemm1_kernel<<<512, 256, 0, stream>>>(x, WT, qb, kb, vb, af);
  scan_kernel<<<256, 256, 0, stream>>>(qb, kb, vb, af, ob);
  gemm2_kernel<<<dim3(8, 512), 256, 0, stream>>>(ob, WoT, out);
}